// Round 1
// baseline (182.895 us; speedup 1.0000x reference)
//
#include <hip/hip_runtime.h>

// Problem constants: B=4, L=2048, C=64, D=4
#define BB 4
#define LL 2048
#define CC 64
#define DD 4
#define NN (CC * DD * DD)   // 1024 chains per batch
#define AN (CC * DD)        // 256 A-entries per timestep per batch (c*4+i)
#define GG 128              // time chunks
#define TT (LL / GG)        // 16 timesteps per chunk
#define SEGLEN 16           // phase-2 segment length (chunks)
#define NSEG (GG / SEGLEN)  // 8 segments

typedef float f32x4 __attribute__((ext_vector_type(4)));

// Chain n = c*16 + i*4 + j. A index within (b,t): n>>2 = c*4+i = "n4".
// One thread owns the 4 chains (j=0..3) sharing one A value -> float4 X loads.

// Phase 1: per (b, g, n4): chunk aggregate. p = prod A (shared across j),
// s_j = local scan of X (zero seed). agg[(b*G+g)*N + n] = (p_re,p_im,s_re,s_im).
__global__ __launch_bounds__(256) void pscan_phase1(
    const float* __restrict__ A_re, const float* __restrict__ A_im,
    const f32x4* __restrict__ X_re4, const f32x4* __restrict__ X_im4,
    f32x4* __restrict__ agg) {
  int u  = blockIdx.x * 256 + threadIdx.x;   // [0, B*G*AN) = 131072
  int n4 = u & (AN - 1);
  int bg = u >> 8;
  int g  = bg & (GG - 1);
  int b  = bg >> 7;
  int t0 = g * TT;
  int baseA = (b * LL + t0) * AN + n4;       // float index into A
  int baseX = (b * LL + t0) * AN + n4;       // f32x4 index into X (AN vec4/step)

  float p_re = 1.f, p_im = 0.f;
  float s_re[4] = {0.f, 0.f, 0.f, 0.f};
  float s_im[4] = {0.f, 0.f, 0.f, 0.f};

#pragma unroll 8
  for (int t = 0; t < TT; ++t) {
    float are = A_re[baseA + t * AN];
    float aim = A_im[baseA + t * AN];
    f32x4 xr  = X_re4[baseX + t * AN];
    f32x4 xi  = X_im4[baseX + t * AN];
    float npre = are * p_re - aim * p_im;
    float npim = are * p_im + aim * p_re;
    p_re = npre; p_im = npim;
#pragma unroll
    for (int j = 0; j < 4; ++j) {
      float nsre = are * s_re[j] - aim * s_im[j] + xr[j];
      float nsim = are * s_im[j] + aim * s_re[j] + xi[j];
      s_re[j] = nsre; s_im[j] = nsim;
    }
  }
  int ab = (b * GG + g) * NN + n4 * 4;       // f32x4 index; 64 B/thread contiguous
#pragma unroll
  for (int j = 0; j < 4; ++j) {
    f32x4 v = {p_re, p_im, s_re[j], s_im[j]};
    agg[ab + j] = v;
  }
}

// Phase 2a: per (b, n, seg): in-place EXCLUSIVE scan of the segment's 16 chunk
// aggregates; writes segment total to segAgg[(b*NSEG+seg)*N + n].
// combine(run=(rp,rs) earlier, v=(vp,vs) later) = (vp*rp, vp*rs + vs)
__global__ __launch_bounds__(256) void pscan_phase2a(
    f32x4* __restrict__ agg, f32x4* __restrict__ segAgg) {
  int u   = blockIdx.x * 256 + threadIdx.x;  // [0, B*NSEG*NN) = 32768
  int n   = u & (NN - 1);
  int r   = u >> 10;
  int seg = r & (NSEG - 1);
  int b   = r >> 3;
  int base = (b * GG + seg * SEGLEN) * NN + n;

  f32x4 v[SEGLEN];
#pragma unroll
  for (int t = 0; t < SEGLEN; ++t) v[t] = agg[base + t * NN];

  float rp_re = 1.f, rp_im = 0.f, rs_re = 0.f, rs_im = 0.f;
#pragma unroll
  for (int t = 0; t < SEGLEN; ++t) {
    f32x4 cur = v[t];
    f32x4 run = {rp_re, rp_im, rs_re, rs_im};
    agg[base + t * NN] = run;
    float np_re = cur.x * rp_re - cur.y * rp_im;
    float np_im = cur.x * rp_im + cur.y * rp_re;
    float ns_re = cur.x * rs_re - cur.y * rs_im + cur.z;
    float ns_im = cur.x * rs_im + cur.y * rs_re + cur.w;
    rp_re = np_re; rp_im = np_im; rs_re = ns_re; rs_im = ns_im;
  }
  f32x4 tot = {rp_re, rp_im, rs_re, rs_im};
  segAgg[(b * NSEG + seg) * NN + n] = tot;
}

// Phase 2b: per (b, n): in-place exclusive scan of the NSEG segment totals.
__global__ __launch_bounds__(256) void pscan_phase2b(f32x4* __restrict__ segAgg) {
  int u = blockIdx.x * 256 + threadIdx.x;    // [0, B*NN) = 4096
  int n = u & (NN - 1);
  int b = u >> 10;
  int base = b * NSEG * NN + n;

  f32x4 v[NSEG];
#pragma unroll
  for (int s = 0; s < NSEG; ++s) v[s] = segAgg[base + s * NN];

  float rp_re = 1.f, rp_im = 0.f, rs_re = 0.f, rs_im = 0.f;
#pragma unroll
  for (int s = 0; s < NSEG; ++s) {
    f32x4 cur = v[s];
    f32x4 run = {rp_re, rp_im, rs_re, rs_im};
    segAgg[base + s * NN] = run;
    float np_re = cur.x * rp_re - cur.y * rp_im;
    float np_im = cur.x * rp_im + cur.y * rp_re;
    float ns_re = cur.x * rs_re - cur.y * rs_im + cur.z;
    float ns_im = cur.x * rs_im + cur.y * rs_re + cur.w;
    rp_re = np_re; rp_im = np_im; rs_re = ns_re; rs_im = ns_im;
  }
}

// Phase 3: per (b, g, n4): full carry = combine(segExcl (earlier), localExcl
// (later)); seed y with carry.s, re-run recurrence, nontemporal-store out.
__global__ __launch_bounds__(256) void pscan_phase3(
    const float* __restrict__ A_re, const float* __restrict__ A_im,
    const f32x4* __restrict__ X_re4, const f32x4* __restrict__ X_im4,
    const f32x4* __restrict__ agg, const f32x4* __restrict__ segAgg,
    f32x4* __restrict__ out4) {
  int u  = blockIdx.x * 256 + threadIdx.x;   // [0, B*G*AN) = 131072
  int n4 = u & (AN - 1);
  int bg = u >> 8;
  int g  = bg & (GG - 1);
  int b  = bg >> 7;
  int t0 = g * TT;
  int seg = g >> 4;                          // g / SEGLEN
  int baseA = (b * LL + t0) * AN + n4;
  int baseX = (b * LL + t0) * AN + n4;
  int ab = (b * GG + g) * NN + n4 * 4;
  int sb = (b * NSEG + seg) * NN + n4 * 4;

  float y_re[4], y_im[4];
#pragma unroll
  for (int j = 0; j < 4; ++j) {
    f32x4 la = agg[ab + j];     // (lp, ls): exclusive within segment
    f32x4 sa = segAgg[sb + j];  // (sp, ss): exclusive across segments
    // carry.s = lp*ss + ls
    y_re[j] = la.x * sa.z - la.y * sa.w + la.z;
    y_im[j] = la.x * sa.w + la.y * sa.z + la.w;
  }

  int ob = (b * LL + t0) * (2 * AN) + n4 * 2;  // f32x4 index into out
#pragma unroll 8
  for (int t = 0; t < TT; ++t) {
    float are = A_re[baseA + t * AN];
    float aim = A_im[baseA + t * AN];
    f32x4 xr  = X_re4[baseX + t * AN];
    f32x4 xi  = X_im4[baseX + t * AN];
#pragma unroll
    for (int j = 0; j < 4; ++j) {
      float ny_re = are * y_re[j] - aim * y_im[j] + xr[j];
      float ny_im = are * y_im[j] + aim * y_re[j] + xi[j];
      y_re[j] = ny_re; y_im[j] = ny_im;
    }
    f32x4 o0 = {y_re[0], y_im[0], y_re[1], y_im[1]};
    f32x4 o1 = {y_re[2], y_im[2], y_re[3], y_im[3]};
    __builtin_nontemporal_store(o0, &out4[ob + t * (2 * AN)]);
    __builtin_nontemporal_store(o1, &out4[ob + t * (2 * AN) + 1]);
  }
}

extern "C" void kernel_launch(void* const* d_in, const int* in_sizes, int n_in,
                              void* d_out, int out_size, void* d_ws, size_t ws_size,
                              hipStream_t stream) {
  const float* A_re = (const float*)d_in[0];
  const float* A_im = (const float*)d_in[1];
  const f32x4* X_re4 = (const f32x4*)d_in[2];
  const f32x4* X_im4 = (const f32x4*)d_in[3];
  f32x4* out4 = (f32x4*)d_out;

  // workspace layout: agg = B*G*N*16 B = 8 MiB, then segAgg = B*NSEG*N*16 B = 512 KiB
  f32x4* agg    = (f32x4*)d_ws;
  f32x4* segAgg = (f32x4*)((char*)d_ws + (size_t)BB * GG * NN * 16);

  const int total = BB * GG * AN;            // 131072 threads, 512 blocks
  pscan_phase1<<<total / 256, 256, 0, stream>>>(A_re, A_im, X_re4, X_im4, agg);
  pscan_phase2a<<<(BB * NSEG * NN) / 256, 256, 0, stream>>>(agg, segAgg);
  pscan_phase2b<<<(BB * NN) / 256, 256, 0, stream>>>(segAgg);
  pscan_phase3<<<total / 256, 256, 0, stream>>>(A_re, A_im, X_re4, X_im4, agg, segAgg, out4);
}

// Round 2
// 156.102 us; speedup vs baseline: 1.1716x; 1.1716x over previous
//
#include <hip/hip_runtime.h>

// Problem constants: B=4, L=2048, C=64, D=4
#define BB 4
#define LL 2048
#define CC 64
#define DD 4
#define NN (CC * DD * DD)   // 1024 chains per batch
#define AN (CC * DD)        // 256 A-entries per timestep per batch (c*4+i)
#define GG 256              // time chunks
#define TT (LL / GG)        // 8 timesteps per chunk
#define SEGLEN 16           // phase-2 segment length (chunks)
#define NSEG (GG / SEGLEN)  // 16 segments

typedef float f32x4 __attribute__((ext_vector_type(4)));

// Chain n = c*16 + i*4 + j. A index within (b,t): n>>2 = c*4+i = "n4".
// One thread owns the 4 chains (j=0..3) sharing one A value -> float4 X loads.

// Phase 1: per (b, g, n4): chunk aggregate. p = prod A (shared across j),
// s_j = local scan of X (zero seed). agg[(b*G+g)*N + n] = (p_re,p_im,s_re,s_im).
__global__ __launch_bounds__(256) void pscan_phase1(
    const float* __restrict__ A_re, const float* __restrict__ A_im,
    const f32x4* __restrict__ X_re4, const f32x4* __restrict__ X_im4,
    f32x4* __restrict__ agg) {
  int u  = blockIdx.x * 256 + threadIdx.x;   // [0, B*G*AN) = 262144
  int n4 = u & (AN - 1);
  int bg = u >> 8;
  int g  = bg & (GG - 1);
  int b  = bg >> 8;
  int t0 = g * TT;
  int baseA = (b * LL + t0) * AN + n4;       // float index into A
  int baseX = (b * LL + t0) * AN + n4;       // f32x4 index into X (AN vec4/step)

  float p_re = 1.f, p_im = 0.f;
  float s_re[4] = {0.f, 0.f, 0.f, 0.f};
  float s_im[4] = {0.f, 0.f, 0.f, 0.f};

#pragma unroll
  for (int t = 0; t < TT; ++t) {
    float are = A_re[baseA + t * AN];
    float aim = A_im[baseA + t * AN];
    f32x4 xr  = X_re4[baseX + t * AN];
    f32x4 xi  = X_im4[baseX + t * AN];
    float npre = are * p_re - aim * p_im;
    float npim = are * p_im + aim * p_re;
    p_re = npre; p_im = npim;
#pragma unroll
    for (int j = 0; j < 4; ++j) {
      float nsre = are * s_re[j] - aim * s_im[j] + xr[j];
      float nsim = are * s_im[j] + aim * s_re[j] + xi[j];
      s_re[j] = nsre; s_im[j] = nsim;
    }
  }
  int ab = (b * GG + g) * NN + n4 * 4;       // f32x4 index; 64 B/thread contiguous
#pragma unroll
  for (int j = 0; j < 4; ++j) {
    f32x4 v = {p_re, p_im, s_re[j], s_im[j]};
    agg[ab + j] = v;
  }
}

// Phase 2a: per (b, n, seg): in-place EXCLUSIVE scan of the segment's 16 chunk
// aggregates; writes segment total to segAgg[(b*NSEG+seg)*N + n].
// combine(run=(rp,rs) earlier, v=(vp,vs) later) = (vp*rp, vp*rs + vs)
__global__ __launch_bounds__(256) void pscan_phase2a(
    f32x4* __restrict__ agg, f32x4* __restrict__ segAgg) {
  int u   = blockIdx.x * 256 + threadIdx.x;  // [0, B*NSEG*NN) = 65536
  int n   = u & (NN - 1);
  int r   = u >> 10;
  int seg = r & (NSEG - 1);
  int b   = r >> 4;
  int base = (b * GG + seg * SEGLEN) * NN + n;

  f32x4 v[SEGLEN];
#pragma unroll
  for (int t = 0; t < SEGLEN; ++t) v[t] = agg[base + t * NN];

  float rp_re = 1.f, rp_im = 0.f, rs_re = 0.f, rs_im = 0.f;
#pragma unroll
  for (int t = 0; t < SEGLEN; ++t) {
    f32x4 cur = v[t];
    f32x4 run = {rp_re, rp_im, rs_re, rs_im};
    agg[base + t * NN] = run;
    float np_re = cur.x * rp_re - cur.y * rp_im;
    float np_im = cur.x * rp_im + cur.y * rp_re;
    float ns_re = cur.x * rs_re - cur.y * rs_im + cur.z;
    float ns_im = cur.x * rs_im + cur.y * rs_re + cur.w;
    rp_re = np_re; rp_im = np_im; rs_re = ns_re; rs_im = ns_im;
  }
  f32x4 tot = {rp_re, rp_im, rs_re, rs_im};
  segAgg[(b * NSEG + seg) * NN + n] = tot;
}

// Phase 2b: per (b, n): in-place exclusive scan of the NSEG segment totals.
__global__ __launch_bounds__(256) void pscan_phase2b(f32x4* __restrict__ segAgg) {
  int u = blockIdx.x * 256 + threadIdx.x;    // [0, B*NN) = 4096
  int n = u & (NN - 1);
  int b = u >> 10;
  int base = b * NSEG * NN + n;

  f32x4 v[NSEG];
#pragma unroll
  for (int s = 0; s < NSEG; ++s) v[s] = segAgg[base + s * NN];

  float rp_re = 1.f, rp_im = 0.f, rs_re = 0.f, rs_im = 0.f;
#pragma unroll
  for (int s = 0; s < NSEG; ++s) {
    f32x4 cur = v[s];
    f32x4 run = {rp_re, rp_im, rs_re, rs_im};
    segAgg[base + s * NN] = run;
    float np_re = cur.x * rp_re - cur.y * rp_im;
    float np_im = cur.x * rp_im + cur.y * rp_re;
    float ns_re = cur.x * rs_re - cur.y * rs_im + cur.z;
    float ns_im = cur.x * rs_im + cur.y * rs_re + cur.w;
    rp_re = np_re; rp_im = np_im; rs_re = ns_re; rs_im = ns_im;
  }
}

// Phase 3: per (b, g, n4): full carry = combine(segExcl (earlier), localExcl
// (later)); seed y with carry.s, re-run recurrence, store out through L2.
__global__ __launch_bounds__(256) void pscan_phase3(
    const float* __restrict__ A_re, const float* __restrict__ A_im,
    const f32x4* __restrict__ X_re4, const f32x4* __restrict__ X_im4,
    const f32x4* __restrict__ agg, const f32x4* __restrict__ segAgg,
    f32x4* __restrict__ out4) {
  int u  = blockIdx.x * 256 + threadIdx.x;   // [0, B*G*AN) = 262144
  int n4 = u & (AN - 1);
  int bg = u >> 8;
  int g  = bg & (GG - 1);
  int b  = bg >> 8;
  int t0 = g * TT;
  int seg = g >> 4;                          // g / SEGLEN
  int baseA = (b * LL + t0) * AN + n4;
  int baseX = (b * LL + t0) * AN + n4;
  int ab = (b * GG + g) * NN + n4 * 4;
  int sb = (b * NSEG + seg) * NN + n4 * 4;

  float y_re[4], y_im[4];
#pragma unroll
  for (int j = 0; j < 4; ++j) {
    f32x4 la = agg[ab + j];     // (lp, ls): exclusive within segment
    f32x4 sa = segAgg[sb + j];  // (sp, ss): exclusive across segments
    // carry.s = lp*ss + ls
    y_re[j] = la.x * sa.z - la.y * sa.w + la.z;
    y_im[j] = la.x * sa.w + la.y * sa.z + la.w;
  }

  int ob = (b * LL + t0) * (2 * AN) + n4 * 2;  // f32x4 index into out
#pragma unroll
  for (int t = 0; t < TT; ++t) {
    float are = A_re[baseA + t * AN];
    float aim = A_im[baseA + t * AN];
    f32x4 xr  = X_re4[baseX + t * AN];
    f32x4 xi  = X_im4[baseX + t * AN];
#pragma unroll
    for (int j = 0; j < 4; ++j) {
      float ny_re = are * y_re[j] - aim * y_im[j] + xr[j];
      float ny_im = are * y_im[j] + aim * y_re[j] + xi[j];
      y_re[j] = ny_re; y_im[j] = ny_im;
    }
    f32x4 o0 = {y_re[0], y_im[0], y_re[1], y_im[1]};
    f32x4 o1 = {y_re[2], y_im[2], y_re[3], y_im[3]};
    out4[ob + t * (2 * AN)]     = o0;
    out4[ob + t * (2 * AN) + 1] = o1;
  }
}

extern "C" void kernel_launch(void* const* d_in, const int* in_sizes, int n_in,
                              void* d_out, int out_size, void* d_ws, size_t ws_size,
                              hipStream_t stream) {
  const float* A_re = (const float*)d_in[0];
  const float* A_im = (const float*)d_in[1];
  const f32x4* X_re4 = (const f32x4*)d_in[2];
  const f32x4* X_im4 = (const f32x4*)d_in[3];
  f32x4* out4 = (f32x4*)d_out;

  // workspace layout: agg = B*G*N*16 B = 16 MiB, then segAgg = B*NSEG*N*16 B = 1 MiB
  f32x4* agg    = (f32x4*)d_ws;
  f32x4* segAgg = (f32x4*)((char*)d_ws + (size_t)BB * GG * NN * 16);

  const int total = BB * GG * AN;            // 262144 threads, 1024 blocks
  pscan_phase1<<<total / 256, 256, 0, stream>>>(A_re, A_im, X_re4, X_im4, agg);
  pscan_phase2a<<<(BB * NSEG * NN) / 256, 256, 0, stream>>>(agg, segAgg);
  pscan_phase2b<<<(BB * NN) / 256, 256, 0, stream>>>(segAgg);
  pscan_phase3<<<total / 256, 256, 0, stream>>>(A_re, A_im, X_re4, X_im4, agg, segAgg, out4);
}

// Round 3
// 155.533 us; speedup vs baseline: 1.1759x; 1.0037x over previous
//
#include <hip/hip_runtime.h>
#include <hip/hip_cooperative_groups.h>

namespace cg = cooperative_groups;

// Problem constants: B=4, L=2048, C=64, D=4
#define BB 4
#define LL 2048
#define CC 64
#define DD 4
#define NN (CC * DD * DD)   // 1024 chains per batch
#define AN (CC * DD)        // 256 A-entries per timestep per batch (c*4+i)
#define GG 256              // time chunks
#define TT (LL / GG)        // 8 timesteps per chunk
#define SEGLEN 16           // phase-2 segment length (chunks)
#define NSEG (GG / SEGLEN)  // 16 segments

typedef float f32x4 __attribute__((ext_vector_type(4)));

// ---------------------------------------------------------------------------
// Fused cooperative kernel: grid = 1024 blocks x 256 threads (4 blocks/CU).
// Each thread owns (b, g, n4): TT=8 timesteps of the 4 chains j=0..3 that
// share one A value. X and A are loaded ONCE into registers and reused after
// the grid-wide carry scan -> saves the 84 MB re-read of the 3-pass version.
// ---------------------------------------------------------------------------
__global__ __launch_bounds__(256, 4) void pscan_fused(
    const float* __restrict__ A_re, const float* __restrict__ A_im,
    const f32x4* __restrict__ X_re4, const f32x4* __restrict__ X_im4,
    f32x4* __restrict__ agg, f32x4* __restrict__ segAgg,
    f32x4* __restrict__ out4) {
  cg::grid_group grid = cg::this_grid();

  int u  = blockIdx.x * 256 + threadIdx.x;   // [0, B*G*AN) = 262144
  int n4 = u & (AN - 1);
  int bg = u >> 8;
  int g  = bg & (GG - 1);
  int b  = bg >> 8;
  int t0 = g * TT;
  int base = (b * LL + t0) * AN + n4;        // index for A (float) and X (f32x4)

  // ---- load A, X into registers (kept live across the whole kernel) ----
  float ar[TT], ai[TT];
  f32x4 xr[TT], xi[TT];
#pragma unroll
  for (int t = 0; t < TT; ++t) {
    ar[t] = A_re[base + t * AN];
    ai[t] = A_im[base + t * AN];
    xr[t] = X_re4[base + t * AN];
    xi[t] = X_im4[base + t * AN];
  }

  // ---- phase A: local chunk aggregate (p, s_j), zero seed ----
  float p_re = 1.f, p_im = 0.f;
  float s_re[4] = {0.f, 0.f, 0.f, 0.f};
  float s_im[4] = {0.f, 0.f, 0.f, 0.f};
#pragma unroll
  for (int t = 0; t < TT; ++t) {
    float are = ar[t], aim = ai[t];
    float npre = are * p_re - aim * p_im;
    float npim = are * p_im + aim * p_re;
    p_re = npre; p_im = npim;
#pragma unroll
    for (int j = 0; j < 4; ++j) {
      float nsre = are * s_re[j] - aim * s_im[j] + xr[t][j];
      float nsim = are * s_im[j] + aim * s_re[j] + xi[t][j];
      s_re[j] = nsre; s_im[j] = nsim;
    }
  }
  int ab = (b * GG + g) * NN + n4 * 4;
#pragma unroll
  for (int j = 0; j < 4; ++j) {
    f32x4 v = {p_re, p_im, s_re[j], s_im[j]};
    agg[ab + j] = v;
  }

  __threadfence();
  grid.sync();
  __threadfence();

  // ---- phase B: exclusive scan of 16 chunk aggs per segment (65536 thr) ----
  if (u < BB * NSEG * NN) {
    int n   = u & (NN - 1);
    int r   = u >> 10;
    int seg = r & (NSEG - 1);
    int b2  = r >> 4;
    int base2 = (b2 * GG + seg * SEGLEN) * NN + n;
    float rp_re = 1.f, rp_im = 0.f, rs_re = 0.f, rs_im = 0.f;
    for (int t = 0; t < SEGLEN; ++t) {
      f32x4 cur = agg[base2 + t * NN];
      f32x4 run = {rp_re, rp_im, rs_re, rs_im};
      agg[base2 + t * NN] = run;
      float np_re = cur.x * rp_re - cur.y * rp_im;
      float np_im = cur.x * rp_im + cur.y * rp_re;
      float ns_re = cur.x * rs_re - cur.y * rs_im + cur.z;
      float ns_im = cur.x * rs_im + cur.y * rs_re + cur.w;
      rp_re = np_re; rp_im = np_im; rs_re = ns_re; rs_im = ns_im;
    }
    f32x4 tot = {rp_re, rp_im, rs_re, rs_im};
    segAgg[(b2 * NSEG + seg) * NN + n] = tot;
  }

  __threadfence();
  grid.sync();
  __threadfence();

  // ---- phase C: exclusive scan of the NSEG segment totals (4096 thr) ----
  if (u < BB * NN) {
    int n  = u & (NN - 1);
    int b3 = u >> 10;
    int base3 = b3 * NSEG * NN + n;
    float rp_re = 1.f, rp_im = 0.f, rs_re = 0.f, rs_im = 0.f;
    for (int s = 0; s < NSEG; ++s) {
      f32x4 cur = segAgg[base3 + s * NN];
      f32x4 run = {rp_re, rp_im, rs_re, rs_im};
      segAgg[base3 + s * NN] = run;
      float np_re = cur.x * rp_re - cur.y * rp_im;
      float np_im = cur.x * rp_im + cur.y * rp_re;
      float ns_re = cur.x * rs_re - cur.y * rs_im + cur.z;
      float ns_im = cur.x * rs_im + cur.y * rs_re + cur.w;
      rp_re = np_re; rp_im = np_im; rs_re = ns_re; rs_im = ns_im;
    }
  }

  __threadfence();
  grid.sync();
  __threadfence();

  // ---- phase D: carry = combine(segExcl, localExcl); recompute from regs ----
  int sb = (b * NSEG + (g >> 4)) * NN + n4 * 4;
  float y_re[4], y_im[4];
#pragma unroll
  for (int j = 0; j < 4; ++j) {
    f32x4 la = agg[ab + j];     // (lp, ls): exclusive within segment
    f32x4 sa = segAgg[sb + j];  // (sp, ss): exclusive across segments
    y_re[j] = la.x * sa.z - la.y * sa.w + la.z;   // carry.s = lp*ss + ls
    y_im[j] = la.x * sa.w + la.y * sa.z + la.w;
  }

  int ob = (b * LL + t0) * (2 * AN) + n4 * 2;
#pragma unroll
  for (int t = 0; t < TT; ++t) {
    float are = ar[t], aim = ai[t];
#pragma unroll
    for (int j = 0; j < 4; ++j) {
      float ny_re = are * y_re[j] - aim * y_im[j] + xr[t][j];
      float ny_im = are * y_im[j] + aim * y_re[j] + xi[t][j];
      y_re[j] = ny_re; y_im[j] = ny_im;
    }
    f32x4 o0 = {y_re[0], y_im[0], y_re[1], y_im[1]};
    f32x4 o1 = {y_re[2], y_im[2], y_re[3], y_im[3]};
    out4[ob + t * (2 * AN)]     = o0;
    out4[ob + t * (2 * AN) + 1] = o1;
  }
}

// ---------------------------------------------------------------------------
// Fallback path (verified round-2 kernels) in case cooperative launch is
// unavailable or the 1024-block co-residency check fails.
// ---------------------------------------------------------------------------
__global__ __launch_bounds__(256) void pscan_phase1(
    const float* __restrict__ A_re, const float* __restrict__ A_im,
    const f32x4* __restrict__ X_re4, const f32x4* __restrict__ X_im4,
    f32x4* __restrict__ agg) {
  int u  = blockIdx.x * 256 + threadIdx.x;
  int n4 = u & (AN - 1);
  int bg = u >> 8;
  int g  = bg & (GG - 1);
  int b  = bg >> 8;
  int t0 = g * TT;
  int base = (b * LL + t0) * AN + n4;

  float p_re = 1.f, p_im = 0.f;
  float s_re[4] = {0.f, 0.f, 0.f, 0.f};
  float s_im[4] = {0.f, 0.f, 0.f, 0.f};
#pragma unroll
  for (int t = 0; t < TT; ++t) {
    float are = A_re[base + t * AN];
    float aim = A_im[base + t * AN];
    f32x4 xrv = X_re4[base + t * AN];
    f32x4 xiv = X_im4[base + t * AN];
    float npre = are * p_re - aim * p_im;
    float npim = are * p_im + aim * p_re;
    p_re = npre; p_im = npim;
#pragma unroll
    for (int j = 0; j < 4; ++j) {
      float nsre = are * s_re[j] - aim * s_im[j] + xrv[j];
      float nsim = are * s_im[j] + aim * s_re[j] + xiv[j];
      s_re[j] = nsre; s_im[j] = nsim;
    }
  }
  int ab = (b * GG + g) * NN + n4 * 4;
#pragma unroll
  for (int j = 0; j < 4; ++j) {
    f32x4 v = {p_re, p_im, s_re[j], s_im[j]};
    agg[ab + j] = v;
  }
}

__global__ __launch_bounds__(256) void pscan_phase2a(
    f32x4* __restrict__ agg, f32x4* __restrict__ segAgg) {
  int u   = blockIdx.x * 256 + threadIdx.x;
  int n   = u & (NN - 1);
  int r   = u >> 10;
  int seg = r & (NSEG - 1);
  int b   = r >> 4;
  int base = (b * GG + seg * SEGLEN) * NN + n;
  float rp_re = 1.f, rp_im = 0.f, rs_re = 0.f, rs_im = 0.f;
  for (int t = 0; t < SEGLEN; ++t) {
    f32x4 cur = agg[base + t * NN];
    f32x4 run = {rp_re, rp_im, rs_re, rs_im};
    agg[base + t * NN] = run;
    float np_re = cur.x * rp_re - cur.y * rp_im;
    float np_im = cur.x * rp_im + cur.y * rp_re;
    float ns_re = cur.x * rs_re - cur.y * rs_im + cur.z;
    float ns_im = cur.x * rs_im + cur.y * rs_re + cur.w;
    rp_re = np_re; rp_im = np_im; rs_re = ns_re; rs_im = ns_im;
  }
  f32x4 tot = {rp_re, rp_im, rs_re, rs_im};
  segAgg[(b * NSEG + seg) * NN + n] = tot;
}

__global__ __launch_bounds__(256) void pscan_phase2b(f32x4* __restrict__ segAgg) {
  int u = blockIdx.x * 256 + threadIdx.x;
  int n = u & (NN - 1);
  int b = u >> 10;
  int base = b * NSEG * NN + n;
  float rp_re = 1.f, rp_im = 0.f, rs_re = 0.f, rs_im = 0.f;
  for (int s = 0; s < NSEG; ++s) {
    f32x4 cur = segAgg[base + s * NN];
    f32x4 run = {rp_re, rp_im, rs_re, rs_im};
    segAgg[base + s * NN] = run;
    float np_re = cur.x * rp_re - cur.y * rp_im;
    float np_im = cur.x * rp_im + cur.y * rp_re;
    float ns_re = cur.x * rs_re - cur.y * rs_im + cur.z;
    float ns_im = cur.x * rs_im + cur.y * rs_re + cur.w;
    rp_re = np_re; rp_im = np_im; rs_re = ns_re; rs_im = ns_im;
  }
}

__global__ __launch_bounds__(256) void pscan_phase3(
    const float* __restrict__ A_re, const float* __restrict__ A_im,
    const f32x4* __restrict__ X_re4, const f32x4* __restrict__ X_im4,
    const f32x4* __restrict__ agg, const f32x4* __restrict__ segAgg,
    f32x4* __restrict__ out4) {
  int u  = blockIdx.x * 256 + threadIdx.x;
  int n4 = u & (AN - 1);
  int bg = u >> 8;
  int g  = bg & (GG - 1);
  int b  = bg >> 8;
  int t0 = g * TT;
  int base = (b * LL + t0) * AN + n4;
  int ab = (b * GG + g) * NN + n4 * 4;
  int sb = (b * NSEG + (g >> 4)) * NN + n4 * 4;

  float y_re[4], y_im[4];
#pragma unroll
  for (int j = 0; j < 4; ++j) {
    f32x4 la = agg[ab + j];
    f32x4 sa = segAgg[sb + j];
    y_re[j] = la.x * sa.z - la.y * sa.w + la.z;
    y_im[j] = la.x * sa.w + la.y * sa.z + la.w;
  }
  int ob = (b * LL + t0) * (2 * AN) + n4 * 2;
#pragma unroll
  for (int t = 0; t < TT; ++t) {
    float are = A_re[base + t * AN];
    float aim = A_im[base + t * AN];
    f32x4 xrv = X_re4[base + t * AN];
    f32x4 xiv = X_im4[base + t * AN];
#pragma unroll
    for (int j = 0; j < 4; ++j) {
      float ny_re = are * y_re[j] - aim * y_im[j] + xrv[j];
      float ny_im = are * y_im[j] + aim * y_re[j] + xiv[j];
      y_re[j] = ny_re; y_im[j] = ny_im;
    }
    f32x4 o0 = {y_re[0], y_im[0], y_re[1], y_im[1]};
    f32x4 o1 = {y_re[2], y_im[2], y_re[3], y_im[3]};
    out4[ob + t * (2 * AN)]     = o0;
    out4[ob + t * (2 * AN) + 1] = o1;
  }
}

extern "C" void kernel_launch(void* const* d_in, const int* in_sizes, int n_in,
                              void* d_out, int out_size, void* d_ws, size_t ws_size,
                              hipStream_t stream) {
  const float* A_re = (const float*)d_in[0];
  const float* A_im = (const float*)d_in[1];
  const f32x4* X_re4 = (const f32x4*)d_in[2];
  const f32x4* X_im4 = (const f32x4*)d_in[3];
  f32x4* out4 = (f32x4*)d_out;

  // workspace: agg = B*G*N*16 B = 16 MiB, then segAgg = 1 MiB
  f32x4* agg    = (f32x4*)d_ws;
  f32x4* segAgg = (f32x4*)((char*)d_ws + (size_t)BB * GG * NN * 16);

  const int total  = BB * GG * AN;           // 262144 threads
  const int blocks = total / 256;            // 1024 blocks

  // One-time check: can 1024 blocks of pscan_fused be co-resident?
  static int coop_ok = -1;
  if (coop_ok < 0) {
    int dev = 0, ncu = 0, coop = 0, maxb = 0;
    hipGetDevice(&dev);
    hipDeviceGetAttribute(&ncu, hipDeviceAttributeMultiprocessorCount, dev);
    hipDeviceGetAttribute(&coop, hipDeviceAttributeCooperativeLaunch, dev);
    hipOccupancyMaxActiveBlocksPerMultiprocessor(&maxb, pscan_fused, 256, 0);
    coop_ok = (coop && ncu > 0 && maxb * ncu >= blocks) ? 1 : 0;
  }

  if (coop_ok) {
    void* args[] = {(void*)&A_re, (void*)&A_im, (void*)&X_re4, (void*)&X_im4,
                    (void*)&agg, (void*)&segAgg, (void*)&out4};
    hipError_t e = hipLaunchCooperativeKernel(pscan_fused, dim3(blocks), dim3(256),
                                              args, 0, stream);
    if (e == hipSuccess) return;
    coop_ok = 0;  // fall through to the verified multi-kernel path
  }

  pscan_phase1<<<blocks, 256, 0, stream>>>(A_re, A_im, X_re4, X_im4, agg);
  pscan_phase2a<<<(BB * NSEG * NN) / 256, 256, 0, stream>>>(agg, segAgg);
  pscan_phase2b<<<(BB * NN) / 256, 256, 0, stream>>>(segAgg);
  pscan_phase3<<<blocks, 256, 0, stream>>>(A_re, A_im, X_re4, X_im4, agg, segAgg, out4);
}